// Round 7
// baseline (260.931 us; speedup 1.0000x reference)
//
#include <hip/hip_runtime.h>
#include <stdint.h>

#define DIM   1024
#define NB    8
#define NSEQ  1024
#define NP    77
#define NH    16
#define NKVR  1104     // padded key space: text 0..76, hole 77..79, x 80..1103
#define KVP   1104     // Vt row length (kv), multiple of 8
#define NTILE 18       // ceil(1152/64) key tiles of 64
#define PLD   68       // P LDS row stride (f32 elems): 64 + 4 pad

typedef short          bf16x8 __attribute__((ext_vector_type(8)));
typedef float          f32x4  __attribute__((ext_vector_type(4)));
typedef unsigned short u16x8  __attribute__((ext_vector_type(8)));
typedef unsigned short u16x4  __attribute__((ext_vector_type(4)));
typedef unsigned int   u32x4  __attribute__((ext_vector_type(4)));

__device__ __forceinline__ float bf2f(unsigned short h) {
  return __uint_as_float(((unsigned int)h) << 16);
}
__device__ __forceinline__ unsigned short f2bf(float f) {
  unsigned int u = __float_as_uint(f);
  unsigned int r = u + 0x7FFFu + ((u >> 16) & 1u);   // RNE
  return (unsigned short)(r >> 16);
}
// pack two f32 -> 2x bf16 (RNE), lo -> bits[15:0]
__device__ __forceinline__ unsigned int cvt_pk_bf16(float lo, float hi) {
  unsigned int r;
  asm volatile("v_cvt_pk_bf16_f32 %0, %1, %2" : "=v"(r) : "v"(lo), "v"(hi));
  return r;
}

// ---------------------------------------------------------------- casts
__global__ __launch_bounds__(256) void cast_kernel(const float* __restrict__ in,
                                                   unsigned short* __restrict__ out,
                                                   int n4) {
  int i = blockIdx.x * 256 + threadIdx.x;
  if (i >= n4) return;
  float4 v = reinterpret_cast<const float4*>(in)[i];
  u16x4 o;
  o[0] = f2bf(v.x); o[1] = f2bf(v.y); o[2] = f2bf(v.z); o[3] = f2bf(v.w);
  reinterpret_cast<u16x4*>(out)[i] = o;
}

// x [8,1024,1024] f32 -> xkv rows batch*1104 + 80 + r
__global__ __launch_bounds__(256) void cast_x_kernel(const float* __restrict__ in,
                                                     unsigned short* __restrict__ xkv) {
  int i = blockIdx.x * 256 + threadIdx.x;
  if (i >= (NB * NSEQ * DIM) / 4) return;
  const int e    = i * 4;
  const int row  = e >> 10;
  const int cin  = e & 1023;
  const int batch = row >> 10;
  const int r     = row & 1023;
  float4 v = *reinterpret_cast<const float4*>(in + (size_t)e);
  u16x4 o;
  o[0] = f2bf(v.x); o[1] = f2bf(v.y); o[2] = f2bf(v.z); o[3] = f2bf(v.w);
  *reinterpret_cast<u16x4*>(xkv + (size_t)(batch * NKVR + 80 + r) * DIM + cin) = o;
}

// x_text [8,77,1024] f32 -> xkv rows batch*1104 + r
__global__ __launch_bounds__(256) void cast_xt_kernel(const float* __restrict__ in,
                                                      unsigned short* __restrict__ xkv) {
  int i = blockIdx.x * 256 + threadIdx.x;
  if (i >= (NB * NP * DIM) / 4) return;
  const int e    = i * 4;
  const int row  = e >> 10;
  const int cin  = e & 1023;
  const int batch = row / NP;
  const int r     = row - batch * NP;
  float4 v = *reinterpret_cast<const float4*>(in + (size_t)e);
  u16x4 o;
  o[0] = f2bf(v.x); o[1] = f2bf(v.y); o[2] = f2bf(v.z); o[3] = f2bf(v.w);
  *reinterpret_cast<u16x4*>(xkv + (size_t)(batch * NKVR + r) * DIM + cin) = o;
}

// zero xkv hole rows (77..79 per batch)
__global__ __launch_bounds__(256) void zero_hole_kernel(unsigned short* __restrict__ xkv) {
  int i = blockIdx.x * 256 + threadIdx.x;
  if (i >= (NB * 3 * DIM) / 4) return;
  const int e    = i * 4;
  const int row  = e >> 10;
  const int cin  = e & 1023;
  const int batch = row / 3;
  const int hr    = row - batch * 3;
  u16x4 z = {0, 0, 0, 0};
  *reinterpret_cast<u16x4*>(xkv + (size_t)(batch * NKVR + 77 + hr) * DIM + cin) = z;
}

// ------------------------------------------------------- async global->LDS
__device__ __forceinline__ void gload_lds16(const void* g, void* l) {
  __builtin_amdgcn_global_load_lds(
      (const __attribute__((address_space(1))) void*)g,
      (__attribute__((address_space(3))) void*)l, 16, 0, 0);
}

// ---------------------------------------------------------------- fused QKV GEMM
// A = xkv [8832][1024], B = Wqkv [3072][1024] (rows: Wq, Wk, Wv).
// grid: 1656 blocks (69 x 24), XCD-swizzled (1656 = 8*207).
__global__ __launch_bounds__(256) void gemm_qkv(
    const unsigned short* __restrict__ A, const unsigned short* __restrict__ B,
    unsigned short* __restrict__ Qo, unsigned short* __restrict__ Ko,
    unsigned short* __restrict__ Vto) {
  __shared__ __align__(16) unsigned short As[128 * 32];
  __shared__ __align__(16) unsigned short Bs[128 * 32];
  const int id   = blockIdx.x;
  const int sid  = (id & 7) * 207 + (id >> 3);     // XCD swizzle (bijective)
  const int bx   = sid / 24;
  const int by   = sid - bx * 24;
  const int m0   = bx * 128;
  const int n0   = by * 128;
  const int t    = threadIdx.x;
  const int w    = t >> 6;
  const int lane = t & 63;
  const int wr   = w >> 1, wc = w & 1;
  const int lr   = lane & 15;
  const int k0   = (lane >> 4) * 8;

  f32x4 acc[4][4];
#pragma unroll
  for (int i = 0; i < 4; ++i)
#pragma unroll
    for (int j = 0; j < 4; ++j) acc[i][j] = f32x4{0.f, 0.f, 0.f, 0.f};

  for (int kt = 0; kt < 32; ++kt) {
#pragma unroll
    for (int p = 0; p < 2; ++p) {
      const int c   = p * 256 + t;
      const int row = c >> 2;
      const int cid = c & 3;
      gload_lds16(A + (size_t)(m0 + row) * DIM + kt * 32 + cid * 8,
                  (char*)As + p * 4096 + w * 1024);
      gload_lds16(B + (size_t)(n0 + row) * DIM + kt * 32 + cid * 8,
                  (char*)Bs + p * 4096 + w * 1024);
    }
    __syncthreads();
    bf16x8 af[4], bfr[4];
#pragma unroll
    for (int mi = 0; mi < 4; ++mi)
      af[mi] = *reinterpret_cast<const bf16x8*>(As + (wr * 64 + mi * 16 + lr) * 32 + k0);
#pragma unroll
    for (int ni = 0; ni < 4; ++ni)
      bfr[ni] = *reinterpret_cast<const bf16x8*>(Bs + (wc * 64 + ni * 16 + lr) * 32 + k0);
#pragma unroll
    for (int mi = 0; mi < 4; ++mi)
#pragma unroll
      for (int ni = 0; ni < 4; ++ni)
        acc[mi][ni] = __builtin_amdgcn_mfma_f32_16x16x32_bf16(af[mi], bfr[ni], acc[mi][ni], 0, 0, 0);
    __syncthreads();
  }

  const int rq  = lane >> 4;
  const int seg = n0 >> 10;          // 0=Q, 1=K, 2=V
  if (seg == 0) {
#pragma unroll
    for (int mi = 0; mi < 4; ++mi) {
#pragma unroll
      for (int i = 0; i < 4; ++i) {
        const int m     = m0 + wr * 64 + mi * 16 + rq * 4 + i;
        const int batch = m / NKVR;
        const int kv    = m - batch * NKVR;
        if (kv < 80) continue;                       // text/hole rows: no Q
        const size_t qrow = (size_t)batch * NSEQ + (kv - 80);
#pragma unroll
        for (int ni = 0; ni < 4; ++ni) {
          const int col = n0 + wc * 64 + ni * 16 + lr;
          Qo[qrow * DIM + col] = f2bf(acc[mi][ni][i]);
        }
      }
    }
  } else if (seg == 1) {
#pragma unroll
    for (int mi = 0; mi < 4; ++mi) {
#pragma unroll
      for (int i = 0; i < 4; ++i) {
        const int m = m0 + wr * 64 + mi * 16 + rq * 4 + i;
#pragma unroll
        for (int ni = 0; ni < 4; ++ni) {
          const int col = n0 + wc * 64 + ni * 16 + lr - 1024;
          Ko[(size_t)m * DIM + col] = f2bf(acc[mi][ni][i]);
        }
      }
    }
  } else {
#pragma unroll
    for (int mi = 0; mi < 4; ++mi) {
      const int mb    = m0 + wr * 64 + mi * 16 + rq * 4;
      const int batch = mb / NKVR;
      const int kv    = mb - batch * NKVR;           // 4-aligned, no batch crossing
#pragma unroll
      for (int ni = 0; ni < 4; ++ni) {
        const int col = n0 + wc * 64 + ni * 16 + lr - 2048;
        const int hh = col >> 6, dd = col & 63;
        u16x4 o;
        o[0] = f2bf(acc[mi][ni][0]); o[1] = f2bf(acc[mi][ni][1]);
        o[2] = f2bf(acc[mi][ni][2]); o[3] = f2bf(acc[mi][ni][3]);
        *reinterpret_cast<u16x4*>(Vto +
            ((size_t)((batch * NH + hh) * 64 + dd)) * KVP + kv) = o;
      }
    }
  }
}

// ---------------------------------------------------------------- out GEMM
__global__ __launch_bounds__(256) void gemm_out(
    const unsigned short* __restrict__ A, const unsigned short* __restrict__ B,
    float* __restrict__ C, const float* __restrict__ bias) {
  __shared__ __align__(16) unsigned short As[128 * 32];
  __shared__ __align__(16) unsigned short Bs[128 * 32];
  const int t    = threadIdx.x;
  const int w    = t >> 6;
  const int lane = t & 63;
  const int m0   = blockIdx.x * 128;
  const int n0   = blockIdx.y * 128;
  const int wr   = w >> 1, wc = w & 1;
  const int lr   = lane & 15;
  const int k0   = (lane >> 4) * 8;

  f32x4 acc[4][4];
#pragma unroll
  for (int i = 0; i < 4; ++i)
#pragma unroll
    for (int j = 0; j < 4; ++j) acc[i][j] = f32x4{0.f, 0.f, 0.f, 0.f};

  for (int kt = 0; kt < 32; ++kt) {
#pragma unroll
    for (int p = 0; p < 2; ++p) {
      const int c   = p * 256 + t;
      const int row = c >> 2;
      const int cid = c & 3;
      gload_lds16(A + (size_t)(m0 + row) * DIM + kt * 32 + cid * 8,
                  (char*)As + p * 4096 + w * 1024);
      gload_lds16(B + (size_t)(n0 + row) * DIM + kt * 32 + cid * 8,
                  (char*)Bs + p * 4096 + w * 1024);
    }
    __syncthreads();
    bf16x8 af[4], bfr[4];
#pragma unroll
    for (int mi = 0; mi < 4; ++mi)
      af[mi] = *reinterpret_cast<const bf16x8*>(As + (wr * 64 + mi * 16 + lr) * 32 + k0);
#pragma unroll
    for (int ni = 0; ni < 4; ++ni)
      bfr[ni] = *reinterpret_cast<const bf16x8*>(Bs + (wc * 64 + ni * 16 + lr) * 32 + k0);
#pragma unroll
    for (int mi = 0; mi < 4; ++mi)
#pragma unroll
      for (int ni = 0; ni < 4; ++ni)
        acc[mi][ni] = __builtin_amdgcn_mfma_f32_16x16x32_bf16(af[mi], bfr[ni], acc[mi][ni], 0, 0, 0);
    __syncthreads();
  }

  const int rq = lane >> 4;
#pragma unroll
  for (int mi = 0; mi < 4; ++mi) {
#pragma unroll
    for (int i = 0; i < 4; ++i) {
      const int m = m0 + wr * 64 + mi * 16 + rq * 4 + i;
#pragma unroll
      for (int ni = 0; ni < 4; ++ni) {
        const int col = n0 + wc * 64 + ni * 16 + lr;
        C[(size_t)m * DIM + col] = acc[mi][ni][i] + bias[col];
      }
    }
  }
}

// ---------------------------------------------------------------- MFMA attention
// grid (128, 8): x = bh (same bh -> same XCD, K/V L2-resident), y = q-tile.
// 2-tile unrolled K-loop with cross-tile K register double-buffer (bkA/bkB).
__global__ __launch_bounds__(256) void attn_mfma(
    const unsigned short* __restrict__ Q, const unsigned short* __restrict__ K,
    const unsigned short* __restrict__ Vt, const float* __restrict__ gate,
    unsigned short* __restrict__ O) {
  const int wid  = threadIdx.x >> 6;
  const int lane = threadIdx.x & 63;
  const int lr   = lane & 15;
  const int lg   = lane >> 4;
  const int bh   = blockIdx.x;
  const int b    = bh >> 4;
  const int h    = bh & 15;
  const int q0   = blockIdx.y * 128 + wid * 32;

  __shared__ __align__(16) float p_lds[4][32 * PLD];   // per-wave f32 P tile

  bf16x8 aq[2][2];
#pragma unroll
  for (int mi = 0; mi < 2; ++mi)
#pragma unroll
    for (int kf = 0; kf < 2; ++kf)
      aq[mi][kf] = *reinterpret_cast<const bf16x8*>(
          Q + ((size_t)(b * NSEQ + q0 + mi * 16 + lr)) * DIM + h * 64 + kf * 32 + lg * 8);

  f32x4 accO[2][4];
#pragma unroll
  for (int mi = 0; mi < 2; ++mi)
#pragma unroll
    for (int n = 0; n < 4; ++n) accO[mi][n] = f32x4{0.f, 0.f, 0.f, 0.f};
  float lsum[2][4];
#pragma unroll
  for (int mi = 0; mi < 2; ++mi)
#pragma unroll
    for (int r = 0; r < 4; ++r) lsum[mi][r] = 0.f;

  const unsigned short* Kbase  = K  + ((size_t)b * NKVR) * DIM + h * 64 + lg * 8;
  const unsigned short* Vtbase = Vt + ((size_t)((b * NH + h) * 64)) * KVP;
  float* pl = p_lds[wid];

  auto load_k = [&](int kv0, bf16x8 (&bk)[4][2]) {
#pragma unroll
    for (int ni = 0; ni < 4; ++ni) {
      int kvn = kv0 + ni * 16 + lr;
      kvn = kvn < (NKVR - 1) ? kvn : (NKVR - 1);
      const unsigned short* kr = Kbase + (size_t)kvn * DIM;
#pragma unroll
      for (int kf = 0; kf < 2; ++kf)
        bk[ni][kf] = *reinterpret_cast<const bf16x8*>(kr + kf * 32);
    }
  };
  auto load_v = [&](int kv0, bf16x8 (&bv)[4][2]) {
#pragma unroll
    for (int n = 0; n < 4; ++n) {
      const unsigned short* vr = Vtbase + (size_t)(n * 16 + lr) * KVP;
#pragma unroll
      for (int kf = 0; kf < 2; ++kf) {
        int kvb = kv0 + kf * 32 + lg * 8;
        kvb = kvb < (KVP - 8) ? kvb : (KVP - 8);
        bv[n][kf] = *reinterpret_cast<const bf16x8*>(vr + kvb);
      }
    }
  };
  auto qk_sm_pv = [&](int tkv, bf16x8 (&bk)[4][2], bf16x8 (&bv)[4][2]) {
    const int kv0 = tkv * 64;
    f32x4 S[2][4];
#pragma unroll
    for (int mi = 0; mi < 2; ++mi)
#pragma unroll
      for (int ni = 0; ni < 4; ++ni) S[mi][ni] = f32x4{0.f, 0.f, 0.f, 0.f};
#pragma unroll
    for (int ni = 0; ni < 4; ++ni)
#pragma unroll
      for (int kf = 0; kf < 2; ++kf)
#pragma unroll
        for (int mi = 0; mi < 2; ++mi)
          S[mi][ni] = __builtin_amdgcn_mfma_f32_16x16x32_bf16(aq[mi][kf], bk[ni][kf], S[mi][ni], 0, 0, 0);
    if (tkv < 2 || tkv == NTILE - 1) {
#pragma unroll
      for (int ni = 0; ni < 4; ++ni) {
        const int gk = kv0 + ni * 16 + lr;
        const bool bad = (gk == 0) || ((unsigned)(gk - 77) < 3u) || (gk >= NKVR);
        if (bad) {
#pragma unroll
          for (int mi = 0; mi < 2; ++mi)
#pragma unroll
            for (int r = 0; r < 4; ++r) S[mi][ni][r] = -1.0e30f;
        }
      }
    }
#pragma unroll
    for (int mi = 0; mi < 2; ++mi) {
#pragma unroll
      for (int ni = 0; ni < 4; ++ni) {
#pragma unroll
        for (int r = 0; r < 4; ++r)
          S[mi][ni][r] = __expf(0.125f * S[mi][ni][r]);
      }
#pragma unroll
      for (int r = 0; r < 4; ++r)
        lsum[mi][r] += (S[mi][0][r] + S[mi][1][r]) + (S[mi][2][r] + S[mi][3][r]);
#pragma unroll
      for (int ni = 0; ni < 4; ++ni) {
        float* pw = pl + (size_t)(mi * 16 + lg * 4) * PLD + ni * 16 + lr;
        pw[0 * PLD] = S[mi][ni][0];
        pw[1 * PLD] = S[mi][ni][1];
        pw[2 * PLD] = S[mi][ni][2];
        pw[3 * PLD] = S[mi][ni][3];
      }
    }
    bf16x8 pa[2][2];
#pragma unroll
    for (int mi = 0; mi < 2; ++mi) {
#pragma unroll
      for (int kf = 0; kf < 2; ++kf) {
        const float* pr = pl + (size_t)(mi * 16 + lr) * PLD + kf * 32 + lg * 8;
        const float4 pa0 = *reinterpret_cast<const float4*>(pr);
        const float4 pa1 = *reinterpret_cast<const float4*>(pr + 4);
        u32x4 pk;
        pk[0] = cvt_pk_bf16(pa0.x, pa0.y);
        pk[1] = cvt_pk_bf16(pa0.z, pa0.w);
        pk[2] = cvt_pk_bf16(pa1.x, pa1.y);
        pk[3] = cvt_pk_bf16(pa1.z, pa1.w);
        pa[mi][kf] = __builtin_bit_cast(bf16x8, pk);
      }
    }
#pragma unroll
    for (int n = 0; n < 4; ++n)
#pragma unroll
      for (int kf = 0; kf < 2; ++kf)
#pragma unroll
        for (int mi = 0; mi < 2; ++mi)
          accO[mi][n] = __builtin_amdgcn_mfma_f32_16x16x32_bf16(pa[mi][kf], bv[n][kf], accO[mi][n], 0, 0, 0);
  };

  bf16x8 bkA[4][2], bkB[4][2], bvA[4][2], bvB[4][2];
  load_k(0, bkA);
  for (int it = 0; it < NTILE / 2; ++it) {
    const int t0 = 2 * it, t1 = 2 * it + 1;
    load_k(t1 * 64, bkB);        // prefetch K(t1); flies during QK(t0)+softmax(t0)
    load_v(t0 * 64, bvA);        // V(t0); flies during QK(t0)+softmax(t0)
    qk_sm_pv(t0, bkA, bvA);
    load_k((t0 + 2) * 64, bkA);  // prefetch K(next t0) (clamped; harmless at end)
    load_v(t1 * 64, bvB);
    qk_sm_pv(t1, bkB, bvB);
  }

#pragma unroll
  for (int mi = 0; mi < 2; ++mi) {
#pragma unroll
    for (int r = 0; r < 4; ++r) {
      float s = lsum[mi][r];
      s += __shfl_xor(s, 1);
      s += __shfl_xor(s, 2);
      s += __shfl_xor(s, 4);
      s += __shfl_xor(s, 8);
      lsum[mi][r] = 1.f / s;
    }
  }
  const float gv = tanhf(gate[h]);
#pragma unroll
  for (int mi = 0; mi < 2; ++mi) {
#pragma unroll
    for (int n = 0; n < 4; ++n) {
      const float v0 = bf2f(Vtbase[(size_t)(n * 16 + lr) * KVP]);   // key 0
#pragma unroll
      for (int r = 0; r < 4; ++r) {
        const float o = accO[mi][n][r] * lsum[mi][r] + gv * v0;
        const int q = q0 + mi * 16 + lg * 4 + r;
        O[((size_t)(b * NSEQ + q)) * DIM + h * 64 + n * 16 + lr] = f2bf(o);
      }
    }
  }
}

// ---------------------------------------------------------------- LayerNorm
__global__ __launch_bounds__(256) void ln_kernel(const unsigned short* __restrict__ in,
                                                 const float* __restrict__ g,
                                                 const float* __restrict__ beta,
                                                 unsigned short* __restrict__ out) {
  const int row = blockIdx.x;
  const int t   = threadIdx.x;
  const u16x4 hv = *reinterpret_cast<const u16x4*>(in + (size_t)row * DIM + t * 4);
  const float v0 = bf2f(hv[0]), v1 = bf2f(hv[1]), v2 = bf2f(hv[2]), v3 = bf2f(hv[3]);
  float sum = v0 + v1 + v2 + v3;
  float sq  = v0 * v0 + v1 * v1 + v2 * v2 + v3 * v3;
  for (int off = 32; off; off >>= 1) {
    sum += __shfl_xor(sum, off);
    sq  += __shfl_xor(sq, off);
  }
  __shared__ float red[8];
  if ((t & 63) == 0) { red[t >> 6] = sum; red[4 + (t >> 6)] = sq; }
  __syncthreads();
  sum = red[0] + red[1] + red[2] + red[3];
  sq  = red[4] + red[5] + red[6] + red[7];
  const float mu  = sum * (1.f / DIM);
  const float var = sq * (1.f / DIM) - mu * mu;
  const float rs  = 1.f / sqrtf(var + 1e-5f);
  const float4 gv = *reinterpret_cast<const float4*>(g + t * 4);
  const float4 bv = *reinterpret_cast<const float4*>(beta + t * 4);
  u16x4 o;
  o[0] = f2bf((v0 - mu) * rs * gv.x + bv.x);
  o[1] = f2bf((v1 - mu) * rs * gv.y + bv.y);
  o[2] = f2bf((v2 - mu) * rs * gv.z + bv.z);
  o[3] = f2bf((v3 - mu) * rs * gv.w + bv.w);
  *reinterpret_cast<u16x4*>(out + (size_t)row * DIM + t * 4) = o;
}

// ---------------------------------------------------------------- launch
extern "C" void kernel_launch(void* const* d_in, const int* in_sizes, int n_in,
                              void* d_out, int out_size, void* d_ws, size_t ws_size,
                              hipStream_t stream) {
  const float* x    = (const float*)d_in[0];
  const float* xt   = (const float*)d_in[1];
  const float* Wq   = (const float*)d_in[2];
  const float* Wk   = (const float*)d_in[3];
  const float* Wv   = (const float*)d_in[4];
  const float* gate = (const float*)d_in[5];
  const float* lng  = (const float*)d_in[6];
  const float* lnbt = (const float*)d_in[7];
  const float* Wp   = (const float*)d_in[8];
  const float* bp   = (const float*)d_in[9];

  char* ws = (char*)d_ws;
  unsigned short* xkvb = (unsigned short*)(ws + 0);          // 18,087,936
  unsigned short* Wqkv = (unsigned short*)(ws + 18087936);   //  6,291,456
  unsigned short* Qb   = (unsigned short*)(ws + 24379392);   // 16,777,216
  unsigned short* Kb   = (unsigned short*)(ws + 41156608);   // 18,087,936
  unsigned short* Vtb  = (unsigned short*)(ws + 59244544);   // 18,087,936 (end 77,332,480)
  unsigned short* attnb = xkvb;   // xkv dead after QKV GEMM
  unsigned short* lnob  = Qb;     // Q dead after attention
  unsigned short* Wpb   = Wqkv;   // Wqkv dead after QKV GEMM

  cast_x_kernel<<<dim3((NB * NSEQ * DIM / 4 + 255) / 256), 256, 0, stream>>>(x, xkvb);
  cast_xt_kernel<<<dim3((NB * NP * DIM / 4 + 255) / 256), 256, 0, stream>>>(xt, xkvb);
  zero_hole_kernel<<<dim3((NB * 3 * DIM / 4 + 255) / 256), 256, 0, stream>>>(xkvb);
  const int w4 = DIM * DIM / 4;
  cast_kernel<<<dim3((w4 + 255) / 256), 256, 0, stream>>>(Wq, Wqkv, w4);
  cast_kernel<<<dim3((w4 + 255) / 256), 256, 0, stream>>>(Wk, Wqkv + DIM * DIM, w4);
  cast_kernel<<<dim3((w4 + 255) / 256), 256, 0, stream>>>(Wv, Wqkv + 2 * DIM * DIM, w4);

  gemm_qkv<<<dim3(69 * 24), 256, 0, stream>>>(xkvb, Wqkv, Qb, Kb, Vtb);

  attn_mfma<<<dim3(128, 8), 256, 0, stream>>>(Qb, Kb, Vtb, gate, attnb);

  cast_kernel<<<dim3((w4 + 255) / 256), 256, 0, stream>>>(Wp, Wpb, w4);
  ln_kernel<<<dim3(NB * NSEQ), 256, 0, stream>>>(attnb, lng, lnbt, lnob);
  gemm_out<<<dim3(64, 8), 256, 0, stream>>>(lnob, Wpb, (float*)d_out, bp);
}

// Round 8
// 246.363 us; speedup vs baseline: 1.0591x; 1.0591x over previous
//
#include <hip/hip_runtime.h>
#include <stdint.h>

#define DIM   1024
#define NB    8
#define NSEQ  1024
#define NP    77
#define NH    16
#define NKVR  1104     // padded key space: text 0..76, hole 77..79, x 80..1103
#define KVP   1104     // Vt row length (kv), multiple of 8
#define NTILE 18       // ceil(1152/64) key tiles of 64
#define PLD   68       // P LDS row stride (f32 elems): 64 + 4 pad

typedef short          bf16x8 __attribute__((ext_vector_type(8)));
typedef float          f32x4  __attribute__((ext_vector_type(4)));
typedef unsigned short u16x8  __attribute__((ext_vector_type(8)));
typedef unsigned short u16x4  __attribute__((ext_vector_type(4)));
typedef unsigned int   u32x4  __attribute__((ext_vector_type(4)));

__device__ __forceinline__ float bf2f(unsigned short h) {
  return __uint_as_float(((unsigned int)h) << 16);
}
__device__ __forceinline__ unsigned short f2bf(float f) {
  unsigned int u = __float_as_uint(f);
  unsigned int r = u + 0x7FFFu + ((u >> 16) & 1u);   // RNE
  return (unsigned short)(r >> 16);
}
// pack two f32 -> 2x bf16 (RNE), lo -> bits[15:0]
__device__ __forceinline__ unsigned int cvt_pk_bf16(float lo, float hi) {
  unsigned int r;
  asm volatile("v_cvt_pk_bf16_f32 %0, %1, %2" : "=v"(r) : "v"(lo), "v"(hi));
  return r;
}

// ---------------------------------------------------------------- casts
__global__ __launch_bounds__(256) void cast_kernel(const float* __restrict__ in,
                                                   unsigned short* __restrict__ out,
                                                   int n4) {
  int i = blockIdx.x * 256 + threadIdx.x;
  if (i >= n4) return;
  float4 v = reinterpret_cast<const float4*>(in)[i];
  u16x4 o;
  o[0] = f2bf(v.x); o[1] = f2bf(v.y); o[2] = f2bf(v.z); o[3] = f2bf(v.w);
  reinterpret_cast<u16x4*>(out)[i] = o;
}

// x [8,1024,1024] f32 -> xkv rows batch*1104 + 80 + r
__global__ __launch_bounds__(256) void cast_x_kernel(const float* __restrict__ in,
                                                     unsigned short* __restrict__ xkv) {
  int i = blockIdx.x * 256 + threadIdx.x;
  if (i >= (NB * NSEQ * DIM) / 4) return;
  const int e    = i * 4;
  const int row  = e >> 10;
  const int cin  = e & 1023;
  const int batch = row >> 10;
  const int r     = row & 1023;
  float4 v = *reinterpret_cast<const float4*>(in + (size_t)e);
  u16x4 o;
  o[0] = f2bf(v.x); o[1] = f2bf(v.y); o[2] = f2bf(v.z); o[3] = f2bf(v.w);
  *reinterpret_cast<u16x4*>(xkv + (size_t)(batch * NKVR + 80 + r) * DIM + cin) = o;
}

// x_text [8,77,1024] f32 -> xkv rows batch*1104 + r
__global__ __launch_bounds__(256) void cast_xt_kernel(const float* __restrict__ in,
                                                      unsigned short* __restrict__ xkv) {
  int i = blockIdx.x * 256 + threadIdx.x;
  if (i >= (NB * NP * DIM) / 4) return;
  const int e    = i * 4;
  const int row  = e >> 10;
  const int cin  = e & 1023;
  const int batch = row / NP;
  const int r     = row - batch * NP;
  float4 v = *reinterpret_cast<const float4*>(in + (size_t)e);
  u16x4 o;
  o[0] = f2bf(v.x); o[1] = f2bf(v.y); o[2] = f2bf(v.z); o[3] = f2bf(v.w);
  *reinterpret_cast<u16x4*>(xkv + (size_t)(batch * NKVR + r) * DIM + cin) = o;
}

// zero xkv hole rows (77..79 per batch)
__global__ __launch_bounds__(256) void zero_hole_kernel(unsigned short* __restrict__ xkv) {
  int i = blockIdx.x * 256 + threadIdx.x;
  if (i >= (NB * 3 * DIM) / 4) return;
  const int e    = i * 4;
  const int row  = e >> 10;
  const int cin  = e & 1023;
  const int batch = row / 3;
  const int hr    = row - batch * 3;
  u16x4 z = {0, 0, 0, 0};
  *reinterpret_cast<u16x4*>(xkv + (size_t)(batch * NKVR + 77 + hr) * DIM + cin) = z;
}

// ------------------------------------------------------- async global->LDS
__device__ __forceinline__ void gload_lds16(const void* g, void* l) {
  __builtin_amdgcn_global_load_lds(
      (const __attribute__((address_space(1))) void*)g,
      (__attribute__((address_space(3))) void*)l, 16, 0, 0);
}

// ---------------------------------------------------------------- fused QKV GEMM
// A = xkv [8832][1024], B = Wqkv [3072][1024] (rows: Wq, Wk, Wv).
// grid: 1656 blocks (69 x 24), XCD-swizzled (1656 = 8*207).
__global__ __launch_bounds__(256) void gemm_qkv(
    const unsigned short* __restrict__ A, const unsigned short* __restrict__ B,
    unsigned short* __restrict__ Qo, unsigned short* __restrict__ Ko,
    unsigned short* __restrict__ Vto) {
  __shared__ __align__(16) unsigned short As[128 * 32];
  __shared__ __align__(16) unsigned short Bs[128 * 32];
  const int id   = blockIdx.x;
  const int sid  = (id & 7) * 207 + (id >> 3);     // XCD swizzle (bijective)
  const int bx   = sid / 24;
  const int by   = sid - bx * 24;
  const int m0   = bx * 128;
  const int n0   = by * 128;
  const int t    = threadIdx.x;
  const int w    = t >> 6;
  const int lane = t & 63;
  const int wr   = w >> 1, wc = w & 1;
  const int lr   = lane & 15;
  const int k0   = (lane >> 4) * 8;

  f32x4 acc[4][4];
#pragma unroll
  for (int i = 0; i < 4; ++i)
#pragma unroll
    for (int j = 0; j < 4; ++j) acc[i][j] = f32x4{0.f, 0.f, 0.f, 0.f};

  for (int kt = 0; kt < 32; ++kt) {
#pragma unroll
    for (int p = 0; p < 2; ++p) {
      const int c   = p * 256 + t;
      const int row = c >> 2;
      const int cid = c & 3;
      gload_lds16(A + (size_t)(m0 + row) * DIM + kt * 32 + cid * 8,
                  (char*)As + p * 4096 + w * 1024);
      gload_lds16(B + (size_t)(n0 + row) * DIM + kt * 32 + cid * 8,
                  (char*)Bs + p * 4096 + w * 1024);
    }
    __syncthreads();
    bf16x8 af[4], bfr[4];
#pragma unroll
    for (int mi = 0; mi < 4; ++mi)
      af[mi] = *reinterpret_cast<const bf16x8*>(As + (wr * 64 + mi * 16 + lr) * 32 + k0);
#pragma unroll
    for (int ni = 0; ni < 4; ++ni)
      bfr[ni] = *reinterpret_cast<const bf16x8*>(Bs + (wc * 64 + ni * 16 + lr) * 32 + k0);
#pragma unroll
    for (int mi = 0; mi < 4; ++mi)
#pragma unroll
      for (int ni = 0; ni < 4; ++ni)
        acc[mi][ni] = __builtin_amdgcn_mfma_f32_16x16x32_bf16(af[mi], bfr[ni], acc[mi][ni], 0, 0, 0);
    __syncthreads();
  }

  const int rq  = lane >> 4;
  const int seg = n0 >> 10;          // 0=Q, 1=K, 2=V
  if (seg == 0) {
#pragma unroll
    for (int mi = 0; mi < 4; ++mi) {
#pragma unroll
      for (int i = 0; i < 4; ++i) {
        const int m     = m0 + wr * 64 + mi * 16 + rq * 4 + i;
        const int batch = m / NKVR;
        const int kv    = m - batch * NKVR;
        if (kv < 80) continue;                       // text/hole rows: no Q
        const size_t qrow = (size_t)batch * NSEQ + (kv - 80);
#pragma unroll
        for (int ni = 0; ni < 4; ++ni) {
          const int col = n0 + wc * 64 + ni * 16 + lr;
          Qo[qrow * DIM + col] = f2bf(acc[mi][ni][i]);
        }
      }
    }
  } else if (seg == 1) {
#pragma unroll
    for (int mi = 0; mi < 4; ++mi) {
#pragma unroll
      for (int i = 0; i < 4; ++i) {
        const int m = m0 + wr * 64 + mi * 16 + rq * 4 + i;
#pragma unroll
        for (int ni = 0; ni < 4; ++ni) {
          const int col = n0 + wc * 64 + ni * 16 + lr - 1024;
          Ko[(size_t)m * DIM + col] = f2bf(acc[mi][ni][i]);
        }
      }
    }
  } else {
#pragma unroll
    for (int mi = 0; mi < 4; ++mi) {
      const int mb    = m0 + wr * 64 + mi * 16 + rq * 4;
      const int batch = mb / NKVR;
      const int kv    = mb - batch * NKVR;           // 4-aligned, no batch crossing
#pragma unroll
      for (int ni = 0; ni < 4; ++ni) {
        const int col = n0 + wc * 64 + ni * 16 + lr - 2048;
        const int hh = col >> 6, dd = col & 63;
        u16x4 o;
        o[0] = f2bf(acc[mi][ni][0]); o[1] = f2bf(acc[mi][ni][1]);
        o[2] = f2bf(acc[mi][ni][2]); o[3] = f2bf(acc[mi][ni][3]);
        *reinterpret_cast<u16x4*>(Vto +
            ((size_t)((batch * NH + hh) * 64 + dd)) * KVP + kv) = o;
      }
    }
  }
}

// ---------------------------------------------------------------- out GEMM
__global__ __launch_bounds__(256) void gemm_out(
    const unsigned short* __restrict__ A, const unsigned short* __restrict__ B,
    float* __restrict__ C, const float* __restrict__ bias) {
  __shared__ __align__(16) unsigned short As[128 * 32];
  __shared__ __align__(16) unsigned short Bs[128 * 32];
  const int t    = threadIdx.x;
  const int w    = t >> 6;
  const int lane = t & 63;
  const int m0   = blockIdx.x * 128;
  const int n0   = blockIdx.y * 128;
  const int wr   = w >> 1, wc = w & 1;
  const int lr   = lane & 15;
  const int k0   = (lane >> 4) * 8;

  f32x4 acc[4][4];
#pragma unroll
  for (int i = 0; i < 4; ++i)
#pragma unroll
    for (int j = 0; j < 4; ++j) acc[i][j] = f32x4{0.f, 0.f, 0.f, 0.f};

  for (int kt = 0; kt < 32; ++kt) {
#pragma unroll
    for (int p = 0; p < 2; ++p) {
      const int c   = p * 256 + t;
      const int row = c >> 2;
      const int cid = c & 3;
      gload_lds16(A + (size_t)(m0 + row) * DIM + kt * 32 + cid * 8,
                  (char*)As + p * 4096 + w * 1024);
      gload_lds16(B + (size_t)(n0 + row) * DIM + kt * 32 + cid * 8,
                  (char*)Bs + p * 4096 + w * 1024);
    }
    __syncthreads();
    bf16x8 af[4], bfr[4];
#pragma unroll
    for (int mi = 0; mi < 4; ++mi)
      af[mi] = *reinterpret_cast<const bf16x8*>(As + (wr * 64 + mi * 16 + lr) * 32 + k0);
#pragma unroll
    for (int ni = 0; ni < 4; ++ni)
      bfr[ni] = *reinterpret_cast<const bf16x8*>(Bs + (wc * 64 + ni * 16 + lr) * 32 + k0);
#pragma unroll
    for (int mi = 0; mi < 4; ++mi)
#pragma unroll
      for (int ni = 0; ni < 4; ++ni)
        acc[mi][ni] = __builtin_amdgcn_mfma_f32_16x16x32_bf16(af[mi], bfr[ni], acc[mi][ni], 0, 0, 0);
    __syncthreads();
  }

  const int rq = lane >> 4;
#pragma unroll
  for (int mi = 0; mi < 4; ++mi) {
#pragma unroll
    for (int i = 0; i < 4; ++i) {
      const int m = m0 + wr * 64 + mi * 16 + rq * 4 + i;
#pragma unroll
      for (int ni = 0; ni < 4; ++ni) {
        const int col = n0 + wc * 64 + ni * 16 + lr;
        C[(size_t)m * DIM + col] = acc[mi][ni][i] + bias[col];
      }
    }
  }
}

// ---------------------------------------------------------------- MFMA attention
// grid (128, 8): x = bh (same bh -> same XCD, K/V L2-resident), y = q-tile.
// Single-buffered per-tile pipeline (R5): K batch-load -> QK -> V issue-early
// -> mask/exp/P-LDS -> PV from registers. VGPR ~100, 4 waves/block.
__global__ __launch_bounds__(256) void attn_mfma(
    const unsigned short* __restrict__ Q, const unsigned short* __restrict__ K,
    const unsigned short* __restrict__ Vt, const float* __restrict__ gate,
    unsigned short* __restrict__ O) {
  const int wid  = threadIdx.x >> 6;
  const int lane = threadIdx.x & 63;
  const int lr   = lane & 15;
  const int lg   = lane >> 4;
  const int bh   = blockIdx.x;
  const int b    = bh >> 4;
  const int h    = bh & 15;
  const int q0   = blockIdx.y * 128 + wid * 32;

  __shared__ __align__(16) float p_lds[4][32 * PLD];   // per-wave f32 P tile

  bf16x8 aq[2][2];
#pragma unroll
  for (int mi = 0; mi < 2; ++mi)
#pragma unroll
    for (int kf = 0; kf < 2; ++kf)
      aq[mi][kf] = *reinterpret_cast<const bf16x8*>(
          Q + ((size_t)(b * NSEQ + q0 + mi * 16 + lr)) * DIM + h * 64 + kf * 32 + lg * 8);

  f32x4 accO[2][4];
#pragma unroll
  for (int mi = 0; mi < 2; ++mi)
#pragma unroll
    for (int n = 0; n < 4; ++n) accO[mi][n] = f32x4{0.f, 0.f, 0.f, 0.f};
  float lsum[2][4];
#pragma unroll
  for (int mi = 0; mi < 2; ++mi)
#pragma unroll
    for (int r = 0; r < 4; ++r) lsum[mi][r] = 0.f;

  const unsigned short* Kbase  = K  + ((size_t)b * NKVR) * DIM + h * 64 + lg * 8;
  const unsigned short* Vtbase = Vt + ((size_t)((b * NH + h) * 64)) * KVP;
  float* pl = p_lds[wid];

  for (int tkv = 0; tkv < NTILE; ++tkv) {
    const int kv0 = tkv * 64;
    // ---- issue all K loads for this tile (batched; consumed by QK below)
    bf16x8 bk[4][2];
#pragma unroll
    for (int ni = 0; ni < 4; ++ni) {
      int kvn = kv0 + ni * 16 + lr;
      kvn = kvn < (NKVR - 1) ? kvn : (NKVR - 1);
      const unsigned short* kr = Kbase + (size_t)kvn * DIM;
#pragma unroll
      for (int kf = 0; kf < 2; ++kf)
        bk[ni][kf] = *reinterpret_cast<const bf16x8*>(kr + kf * 32);
    }
    // ---- S = Q K^T
    f32x4 S[2][4];
#pragma unroll
    for (int mi = 0; mi < 2; ++mi)
#pragma unroll
      for (int ni = 0; ni < 4; ++ni) S[mi][ni] = f32x4{0.f, 0.f, 0.f, 0.f};
#pragma unroll
    for (int ni = 0; ni < 4; ++ni)
#pragma unroll
      for (int kf = 0; kf < 2; ++kf)
#pragma unroll
        for (int mi = 0; mi < 2; ++mi)
          S[mi][ni] = __builtin_amdgcn_mfma_f32_16x16x32_bf16(aq[mi][kf], bk[ni][kf], S[mi][ni], 0, 0, 0);
    // ---- issue all V loads now; they fly during exp + P-LDS roundtrip
    bf16x8 bv[4][2];
#pragma unroll
    for (int n = 0; n < 4; ++n) {
      const unsigned short* vr = Vtbase + (size_t)(n * 16 + lr) * KVP;
#pragma unroll
      for (int kf = 0; kf < 2; ++kf) {
        int kvb = kv0 + kf * 32 + lg * 8;
        kvb = kvb < (KVP - 8) ? kvb : (KVP - 8);
        bv[n][kf] = *reinterpret_cast<const bf16x8*>(vr + kvb);
      }
    }
    // ---- mask (tiles containing key 0, the hole 77..79, or tail >=1104)
    if (tkv < 2 || tkv == NTILE - 1) {
#pragma unroll
      for (int ni = 0; ni < 4; ++ni) {
        const int gk = kv0 + ni * 16 + lr;
        const bool bad = (gk == 0) || ((unsigned)(gk - 77) < 3u) || (gk >= NKVR);
        if (bad) {
#pragma unroll
          for (int mi = 0; mi < 2; ++mi)
#pragma unroll
            for (int r = 0; r < 4; ++r) S[mi][ni][r] = -1.0e30f;
        }
      }
    }
    // ---- exp (no max subtraction), per-lane partial sums, P -> LDS (f32)
#pragma unroll
    for (int mi = 0; mi < 2; ++mi) {
#pragma unroll
      for (int ni = 0; ni < 4; ++ni) {
#pragma unroll
        for (int r = 0; r < 4; ++r)
          S[mi][ni][r] = __expf(0.125f * S[mi][ni][r]);
      }
#pragma unroll
      for (int r = 0; r < 4; ++r)
        lsum[mi][r] += (S[mi][0][r] + S[mi][1][r]) + (S[mi][2][r] + S[mi][3][r]);
#pragma unroll
      for (int ni = 0; ni < 4; ++ni) {
        float* pw = pl + (size_t)(mi * 16 + lg * 4) * PLD + ni * 16 + lr;
        pw[0 * PLD] = S[mi][ni][0];
        pw[1 * PLD] = S[mi][ni][1];
        pw[2 * PLD] = S[mi][ni][2];
        pw[3 * PLD] = S[mi][ni][3];
      }
    }
    // ---- O += P V
    bf16x8 pa[2][2];
#pragma unroll
    for (int mi = 0; mi < 2; ++mi) {
#pragma unroll
      for (int kf = 0; kf < 2; ++kf) {
        const float* pr = pl + (size_t)(mi * 16 + lr) * PLD + kf * 32 + lg * 8;
        const float4 pa0 = *reinterpret_cast<const float4*>(pr);
        const float4 pa1 = *reinterpret_cast<const float4*>(pr + 4);
        u32x4 pk;
        pk[0] = cvt_pk_bf16(pa0.x, pa0.y);
        pk[1] = cvt_pk_bf16(pa0.z, pa0.w);
        pk[2] = cvt_pk_bf16(pa1.x, pa1.y);
        pk[3] = cvt_pk_bf16(pa1.z, pa1.w);
        pa[mi][kf] = __builtin_bit_cast(bf16x8, pk);
      }
    }
#pragma unroll
    for (int n = 0; n < 4; ++n)
#pragma unroll
      for (int kf = 0; kf < 2; ++kf)
#pragma unroll
        for (int mi = 0; mi < 2; ++mi)
          accO[mi][n] = __builtin_amdgcn_mfma_f32_16x16x32_bf16(pa[mi][kf], bv[n][kf], accO[mi][n], 0, 0, 0);
  }

  // ---- single cross-lane sum reduce, then epilogue
#pragma unroll
  for (int mi = 0; mi < 2; ++mi) {
#pragma unroll
    for (int r = 0; r < 4; ++r) {
      float s = lsum[mi][r];
      s += __shfl_xor(s, 1);
      s += __shfl_xor(s, 2);
      s += __shfl_xor(s, 4);
      s += __shfl_xor(s, 8);
      lsum[mi][r] = 1.f / s;
    }
  }
  const float gv = tanhf(gate[h]);
#pragma unroll
  for (int mi = 0; mi < 2; ++mi) {
#pragma unroll
    for (int n = 0; n < 4; ++n) {
      const float v0 = bf2f(Vtbase[(size_t)(n * 16 + lr) * KVP]);   // key 0
#pragma unroll
      for (int r = 0; r < 4; ++r) {
        const float o = accO[mi][n][r] * lsum[mi][r] + gv * v0;
        const int q = q0 + mi * 16 + lg * 4 + r;
        O[((size_t)(b * NSEQ + q)) * DIM + h * 64 + n * 16 + lr] = f2bf(o);
      }
    }
  }
}

// ---------------------------------------------------------------- LayerNorm
__global__ __launch_bounds__(256) void ln_kernel(const unsigned short* __restrict__ in,
                                                 const float* __restrict__ g,
                                                 const float* __restrict__ beta,
                                                 unsigned short* __restrict__ out) {
  const int row = blockIdx.x;
  const int t   = threadIdx.x;
  const u16x4 hv = *reinterpret_cast<const u16x4*>(in + (size_t)row * DIM + t * 4);
  const float v0 = bf2f(hv[0]), v1 = bf2f(hv[1]), v2 = bf2f(hv[2]), v3 = bf2f(hv[3]);
  float sum = v0 + v1 + v2 + v3;
  float sq  = v0 * v0 + v1 * v1 + v2 * v2 + v3 * v3;
  for (int off = 32; off; off >>= 1) {
    sum += __shfl_xor(sum, off);
    sq  += __shfl_xor(sq, off);
  }
  __shared__ float red[8];
  if ((t & 63) == 0) { red[t >> 6] = sum; red[4 + (t >> 6)] = sq; }
  __syncthreads();
  sum = red[0] + red[1] + red[2] + red[3];
  sq  = red[4] + red[5] + red[6] + red[7];
  const float mu  = sum * (1.f / DIM);
  const float var = sq * (1.f / DIM) - mu * mu;
  const float rs  = 1.f / sqrtf(var + 1e-5f);
  const float4 gv = *reinterpret_cast<const float4*>(g + t * 4);
  const float4 bv = *reinterpret_cast<const float4*>(beta + t * 4);
  u16x4 o;
  o[0] = f2bf((v0 - mu) * rs * gv.x + bv.x);
  o[1] = f2bf((v1 - mu) * rs * gv.y + bv.y);
  o[2] = f2bf((v2 - mu) * rs * gv.z + bv.z);
  o[3] = f2bf((v3 - mu) * rs * gv.w + bv.w);
  *reinterpret_cast<u16x4*>(out + (size_t)row * DIM + t * 4) = o;
}

// ---------------------------------------------------------------- launch
extern "C" void kernel_launch(void* const* d_in, const int* in_sizes, int n_in,
                              void* d_out, int out_size, void* d_ws, size_t ws_size,
                              hipStream_t stream) {
  const float* x    = (const float*)d_in[0];
  const float* xt   = (const float*)d_in[1];
  const float* Wq   = (const float*)d_in[2];
  const float* Wk   = (const float*)d_in[3];
  const float* Wv   = (const float*)d_in[4];
  const float* gate = (const float*)d_in[5];
  const float* lng  = (const float*)d_in[6];
  const float* lnbt = (const float*)d_in[7];
  const float* Wp   = (const float*)d_in[8];
  const float* bp   = (const float*)d_in[9];

  char* ws = (char*)d_ws;
  unsigned short* xkvb = (unsigned short*)(ws + 0);          // 18,087,936
  unsigned short* Wqkv = (unsigned short*)(ws + 18087936);   //  6,291,456
  unsigned short* Qb   = (unsigned short*)(ws + 24379392);   // 16,777,216
  unsigned short* Kb   = (unsigned short*)(ws + 41156608);   // 18,087,936
  unsigned short* Vtb  = (unsigned short*)(ws + 59244544);   // 18,087,936 (end 77,332,480)
  unsigned short* attnb = xkvb;   // xkv dead after QKV GEMM
  unsigned short* lnob  = Qb;     // Q dead after attention
  unsigned short* Wpb   = Wqkv;   // Wqkv dead after QKV GEMM

  cast_x_kernel<<<dim3((NB * NSEQ * DIM / 4 + 255) / 256), 256, 0, stream>>>(x, xkvb);
  cast_xt_kernel<<<dim3((NB * NP * DIM / 4 + 255) / 256), 256, 0, stream>>>(xt, xkvb);
  zero_hole_kernel<<<dim3((NB * 3 * DIM / 4 + 255) / 256), 256, 0, stream>>>(xkvb);
  const int w4 = DIM * DIM / 4;
  cast_kernel<<<dim3((w4 + 255) / 256), 256, 0, stream>>>(Wq, Wqkv, w4);
  cast_kernel<<<dim3((w4 + 255) / 256), 256, 0, stream>>>(Wk, Wqkv + DIM * DIM, w4);
  cast_kernel<<<dim3((w4 + 255) / 256), 256, 0, stream>>>(Wv, Wqkv + 2 * DIM * DIM, w4);

  gemm_qkv<<<dim3(69 * 24), 256, 0, stream>>>(xkvb, Wqkv, Qb, Kb, Vtb);

  attn_mfma<<<dim3(128, 8), 256, 0, stream>>>(Qb, Kb, Vtb, gate, attnb);

  cast_kernel<<<dim3((w4 + 255) / 256), 256, 0, stream>>>(Wp, Wpb, w4);
  ln_kernel<<<dim3(NB * NSEQ), 256, 0, stream>>>(attnb, lng, lnbt, lnob);
  gemm_out<<<dim3(64, 8), 256, 0, stream>>>(lnob, Wpb, (float*)d_out, bp);
}